// Round 10
// baseline (7152.570 us; speedup 1.0000x reference)
//
#include <hip/hip_runtime.h>

typedef __bf16 bf16x8 __attribute__((ext_vector_type(8)));
typedef float f32x4 __attribute__((ext_vector_type(4)));
typedef unsigned short u16;
typedef unsigned int u32;
typedef unsigned long long u64;

#define NT 50
#define NB 1024
#define DET 600
#define DP 608        // padded K dim
#define NP 640        // padded N dim (weight rows)
#define HLD 640       // h/x row stride (elements)
#define EMB 1024
#define OUTW 792
#define GBLK 768      // 32 my x 24 ng phase-A tiles; phase B uses bid<256
#define NG 24
#define NCOLS 26      // real output cols per ng group (24*26=624 >= 608)
#define HXS2 ((size_t)NB * HLD)

__device__ __forceinline__ u16 f2bf(float f) {
  unsigned u = __float_as_uint(f);
  u += 0x7FFFu + ((u >> 16) & 1u);
  return (u16)(u >> 16);
}
__device__ __forceinline__ float bf2f(u16 h) { return __uint_as_float(((unsigned)h) << 16); }
__device__ __forceinline__ float eluf(float x) { return x > 0.f ? x : expm1f(x); }
__device__ __forceinline__ float sigm(float x) { return 1.f / (1.f + expf(-x)); }
__device__ __forceinline__ float softplusf(float x) {
  return fmaxf(x, 0.f) + log1pf(expf(-fabsf(x)));
}

__device__ __forceinline__ void gll16(const void* g, void* l) {
  __builtin_amdgcn_global_load_lds(
      (const __attribute__((address_space(1))) u32*)g,
      (__attribute__((address_space(3))) u32*)l, 16, 0, 0);
}

__device__ __forceinline__ u32 ld32sc(const u32* p_) {
  return __hip_atomic_load(p_, __ATOMIC_RELAXED, __HIP_MEMORY_SCOPE_SYSTEM);
}
__device__ __forceinline__ void st32sc(u32* p_, u32 v) {
  __hip_atomic_store(p_, v, __ATOMIC_RELAXED, __HIP_MEMORY_SCOPE_SYSTEM);
}

// Flag-array grid barrier (no atomic RMW). Monotone targets, memset once/launch.
__device__ __forceinline__ void gridbar(u32* bar, u32 target) {
  __syncthreads();
  if (blockIdx.x == 0) {
    if (threadIdx.x < 64) {
      const int l = threadIdx.x;
      for (;;) {
        u32 mn = 0xFFFFFFFFu;
#pragma unroll
        for (int k = 0; k < 12; k++) {
          int idx = l + k * 64;
          u32 v = (idx >= 1 && idx < GBLK) ? ld32sc(&bar[idx]) : target;
          mn = min(mn, v);
        }
        if (__all(mn >= target)) break;
        __builtin_amdgcn_s_sleep(2);
      }
      if (l == 0) st32sc(&bar[960], target);
    }
  } else if (threadIdx.x == 0) {
    st32sc(&bar[blockIdx.x], target);
    while (ld32sc(&bar[960]) < target) __builtin_amdgcn_s_sleep(2);
  }
  __syncthreads();
}

// Swizzled chunk layout for [rows][32] bf16 tiles staged as 16B chunks:
// chunk S holds (row = S>>2, k8 = ((S&3) - ((S>>3)&3)) & 3).
// reader for (row,k8): S = row*4 + ((k8 + (row>>1)) & 3)  -> 2-way banks (free).

struct PK {
  const u16 *W6, *Wp1, *Wq1h, *Wp2, *Wq2, *Winp, *QE;
  const float *b_ih, *b_hh, *bp1, *bq1, *bp2, *bq2, *b_in;
  const float *init_deter, *actions, *nonterm, *noise_p, *noise_q;
  u16 *xbuf, *hbuf;
  float *out;
  u32 *bar;
};

__global__ __launch_bounds__(256, 3) void rssm_persist(PK p)
{
  __shared__ char smem[32768] __attribute__((aligned(16)));

  const int bid = blockIdx.x, tid = threadIdx.x;
  const int lane = tid & 63, w = tid >> 6;
  const int r16 = lane & 15, k8g = lane >> 4;

  // ---- phase A config: 32x26 tile. bid = my*24+ng -> XCD = bid%8 = ng%8
  // (weights XCD-affine: 3 ng-groups/XCD = ~570KB L2-resident).
  const int my = bid / NG, ng = bid - my * NG;
  const int Am0 = my * 32, nbase = ng * NCOLS;
  const int wr = w >> 1, wc = w & 1;

  // staging plan: 16 units of one gll16 (64 chunks) each; wave w takes units
  // w*4..w*4+3. unit u: tile = u>>1 (0:x 1:h 2..7:W sec), half = u&1.
  int skind[4]; size_t ssrc[4]; u32 sdst[4];
#pragma unroll
  for (int q = 0; q < 4; q++) {
    int u = w * 4 + q;
    int S = (u & 1) * 64 + lane;
    int row = S >> 2;
    int k8 = ((S & 3) - ((S >> 3) & 3)) & 3;
    int tile = u >> 1;
    sdst[q] = tile * 2048 + (u & 1) * 1024;
    if (tile < 2) {
      skind[q] = tile;
      ssrc[q] = (size_t)(Am0 + row) * HLD + k8 * 8;
    } else {
      skind[q] = 2;
      ssrc[q] = (size_t)(tile - 2) * NP * DP + (size_t)(nbase + row) * DP + k8 * 8;
    }
  }

  // ---- phase B config: 8-row slices x 2 heads, bid 0..255
  const bool doB = bid < 256;
  const int slice = bid >> 1, head = bid & 1;
  const int Bm0 = slice * 8;
  const u16* W1 = head ? p.Wq1h : p.Wp1;
  const float* b1 = head ? p.bq1 : p.bp1;
  const u16* W2 = head ? p.Wq2 : p.Wp2;
  const float* b2 = head ? p.bq2 : p.bp2;

  u16* hslph = (u16*)smem;                 // hsl [8][616] then ph [16][648] (aliased)
  float* red = (float*)(smem + 20736);     // [3][64][8] f32
  u16* xin = (u16*)(smem + 26880);         // [16][72] bf16

  for (int t = 0; t < NT; ++t) {
    const u16* hprev = p.hbuf + (size_t)t * HXS2;
    u16* hnow = p.hbuf + (size_t)(t + 1) * HXS2;
    const u16* xcur = p.xbuf + (size_t)t * HXS2;
    u16* xnxt = p.xbuf + (size_t)(t + 1) * HXS2;
    float* out_t = p.out + (size_t)t * NB * OUTW;

    // =================== phase A: GRU (all 768 blocks) ===================
    {
      f32x4 acc[6] = {};
      auto stage = [&](int buf, int kc) {
#pragma unroll
        for (int q = 0; q < 4; q++) {
          const u16* mat = (skind[q] == 0) ? xcur : (skind[q] == 1) ? hprev : p.W6;
          gll16(mat + ssrc[q] + kc, smem + buf * 16384 + sdst[q]);
        }
      };
      auto compute = [&](int buf) {
        const char* base = smem + buf * 16384;
        int rowa = wr * 16 + r16;
        int Sa = rowa * 4 + ((k8g + (rowa >> 1)) & 3);
        bf16x8 ax = *(const bf16x8*)(base + Sa * 16);
        bf16x8 ah = *(const bf16x8*)(base + 2048 + Sa * 16);
        int rowb = wc * 16 + r16;
        int Sb = rowb * 4 + ((k8g + (rowb >> 1)) & 3);
#pragma unroll
        for (int s = 0; s < 6; s++) {
          bf16x8 b = *(const bf16x8*)(base + 4096 + s * 2048 + Sb * 16);
          acc[s] = __builtin_amdgcn_mfma_f32_16x16x32_bf16(
              (s < 3) ? ax : ah, b, acc[s], 0, 0, 0);
        }
      };
      stage(0, 0);
      for (int it = 0; it < 19; ++it) {
        if (it + 1 < 19) {
          stage((it + 1) & 1, (it + 1) * 32);
          asm volatile("s_waitcnt vmcnt(4)" ::: "memory");
        } else {
          asm volatile("s_waitcnt vmcnt(0)" ::: "memory");
        }
        __builtin_amdgcn_s_barrier();
        __builtin_amdgcn_sched_barrier(0);
        compute(it & 1);
        __builtin_amdgcn_s_barrier();
      }
      const float* dprev = t ? (out_t - (size_t)NB * OUTW) : p.init_deter;
      const int dstr = t ? OUTW : DET;
      const int local = wc * 16 + r16;
      const int n = nbase + local;
      const bool nok = (local < NCOLS) && (n < DET);
      float bihr = nok ? p.b_ih[n] : 0.f, bhhr = nok ? p.b_hh[n] : 0.f;
      float bihz = nok ? p.b_ih[600 + n] : 0.f, bhhz = nok ? p.b_hh[600 + n] : 0.f;
      float bihn = nok ? p.b_ih[1200 + n] : 0.f, bhhn = nok ? p.b_hh[1200 + n] : 0.f;
#pragma unroll
      for (int r = 0; r < 4; r++) {
        int m = Am0 + wr * 16 + k8g * 4 + r;
        float dp = nok ? dprev[(size_t)m * dstr + n] : 0.f;   // own-L2 hit
        float rg = sigm(acc[0][r] + bihr + acc[3][r] + bhhr);
        float zg = sigm(acc[1][r] + bihz + acc[4][r] + bhhz);
        float ngt = tanhf(acc[2][r] + bihn + rg * (acc[5][r] + bhhn));
        float h = (1.f - zg) * ngt + zg * dp;
        u32 hb16 = f2bf(h);
        u32 other = (u32)__shfl_xor((int)hb16, 1, 64);
        if (nok) {
          out_t[(size_t)m * OUTW + n] = h;                    // plain (local reuse)
          if (!(lane & 1))                                    // SC: cross-XCD
            st32sc((u32*)&hnow[(size_t)m * HLD + n], hb16 | (other << 16));
        }
      }
    }
    gridbar(p.bar, 2 * t + 1);

    // =================== phase B: heads (bid < 256) ===================
    if (doB) {
      const bool donext = (t + 1 < NT);
      const float* noise = (head ? p.noise_q : p.noise_p) + (size_t)t * NB * 32;

      // stage h slice [8][608(+8 pad)] -> hsl (616 chunks of 16B)
      {
        const u16* hrow = hnow + (size_t)Bm0 * HLD;
#pragma unroll
        for (int c = 0; c < 3; ++c) {
          int chunk = c * 256 + tid;
          int ch2 = chunk < 616 ? chunk : 615;
          int row = ch2 / 77, cc = ch2 - row * 77;
          gll16(hrow + (size_t)row * HLD + cc * 8,
                smem + (c * 256 + w * 64) * 16);
        }
      }
      // QE prefetch (rows mr<8 only)
      float qe[10][4] = {};
      if (head) {
        const u16* qbase = p.QE + ((size_t)t * NB + Bm0) * NP;
#pragma unroll
        for (int i = 0; i < 10; i++) {
          int j = w + i * 4;
          if (j < 38) {
            int n = j * 16 + r16;
#pragma unroll
            for (int r = 0; r < 4; r++) {
              int mr = k8g * 4 + r;
              if (mr < 8) qe[i][r] = bf2f(qbase[(size_t)mr * NP + n]);
            }
          }
        }
      }
      if (donext)
        for (int i = tid; i < 576; i += 256) ((u32*)xin)[i] = 0;
      __syncthreads();

      // heads1: [8(pad16) rows] x [608 cols], K=608; A from LDS, W1 from L2
      f32x4 a1[10] = {};
      for (int kc = 0; kc < DP; kc += 32) {
        bf16x8 fa = *(const bf16x8*)&hslph[r16 * 616 + kc + k8g * 8];
#pragma unroll
        for (int i = 0; i < 10; i++) {
          int j = w + i * 4;
          if (j < 38) {
            bf16x8 fb = *(const bf16x8*)&W1[(size_t)(j * 16 + r16) * DP + kc + k8g * 8];
            a1[i] = __builtin_amdgcn_mfma_f32_16x16x32_bf16(fa, fb, a1[i], 0, 0, 0);
          }
        }
      }
      __syncthreads();   // hsl reads done before ph (aliased) writes
      // ph epilogue: elu(+bias +QE) -> LDS bf16 [16][648] (rows>=8 garbage, unused)
#pragma unroll
      for (int i = 0; i < 10; i++) {
        int j = w + i * 4;
        if (j >= 38) break;
        int n = j * 16 + r16;
        if (n >= DET) continue;
#pragma unroll
        for (int r = 0; r < 4; r++) {
          int mrow = k8g * 4 + r;
          float v = a1[i][r] + b1[n] + qe[i][r];
          hslph[mrow * 648 + n] = f2bf(eluf(v));
        }
      }
      __syncthreads();
      // heads2: K=640 split over 4 waves (W2 k-cols >=600 are zero -> ph pad safe)
      f32x4 a2[4] = {};
      {
        int kc0 = w * 160;
#pragma unroll
        for (int ks = 0; ks < 5; ks++) {
          int kc = kc0 + ks * 32;
          bf16x8 fa = *(const bf16x8*)&hslph[r16 * 648 + kc + k8g * 8];
#pragma unroll
          for (int j = 0; j < 4; j++) {
            bf16x8 fb = *(const bf16x8*)&W2[(size_t)(j * 16 + r16) * NP + kc + k8g * 8];
            a2[j] = __builtin_amdgcn_mfma_f32_16x16x32_bf16(fa, fb, a2[j], 0, 0, 0);
          }
        }
      }
      if (w) {
#pragma unroll
        for (int j = 0; j < 4; j++)
#pragma unroll
          for (int r = 0; r < 4; r++) {
            int mr = k8g * 4 + r;
            if (mr < 8) red[(w - 1) * 512 + (j * 16 + r16) * 8 + mr] = a2[j][r];
          }
      }
      __syncthreads();
      if (w == 0) {
        const int ob = head ? 696 : 600;
        const float* ntn = donext ? p.nonterm + (size_t)(t + 1) * NB : nullptr;
#pragma unroll
        for (int j = 0; j < 2; j++) {
          int c = j * 16 + r16;
          float bmu = b2[c], bsd = b2[32 + c];
#pragma unroll
          for (int r = 0; r < 4; r++) {
            int mr = k8g * 4 + r;
            if (mr >= 8) continue;
            int m = Bm0 + mr;
            float mu = a2[j][r] + red[c * 8 + mr] + red[512 + c * 8 + mr]
                     + red[1024 + c * 8 + mr] + bmu;
            float s2 = a2[j + 2][r] + red[(32 + c) * 8 + mr]
                     + red[512 + (32 + c) * 8 + mr] + red[1024 + (32 + c) * 8 + mr] + bsd;
            float sd = softplusf(s2) + 0.1f;
            float st = mu + sd * noise[(size_t)m * 32 + c];
            float* op = out_t + (size_t)m * OUTW + ob;
            op[c] = mu; op[32 + c] = sd; op[64 + c] = st;
            if (head && donext) xin[mr * 72 + c] = f2bf(st * ntn[m]);
          }
        }
      } else if (w == 1 && head && donext) {
        const float* an = p.actions + (size_t)(t + 1) * NB * 6;
        if (lane < 48) {
          int rr = lane / 6, cc = lane - rr * 6;
          xin[rr * 72 + 32 + cc] = f2bf(an[(size_t)(Bm0 + rr) * 6 + cc]);
        }
      }
      if (head && donext) {
        __syncthreads();
        // xnext: elu(xin[8(pad16)][64] @ Winp^T + b_in) -> xbuf[t+1] (SC)
        f32x4 xc[10] = {};
        const int nb = w * 160;
#pragma unroll
        for (int kc = 0; kc < 64; kc += 32) {
          bf16x8 fa = *(const bf16x8*)&xin[r16 * 72 + kc + k8g * 8];
#pragma unroll
          for (int j = 0; j < 10; j++) {
            bf16x8 fb = *(const bf16x8*)&p.Winp[(size_t)(nb + j * 16 + r16) * 64 + kc + k8g * 8];
            xc[j] = __builtin_amdgcn_mfma_f32_16x16x32_bf16(fa, fb, xc[j], 0, 0, 0);
          }
        }
#pragma unroll
        for (int j = 0; j < 10; j++) {
          int n = nb + j * 16 + r16;
          bool nok = (n < DET);
          float bi = nok ? p.b_in[n] : 0.f;
#pragma unroll
          for (int r = 0; r < 4; r++) {
            int mr = k8g * 4 + r;
            float v = eluf(xc[j][r] + bi);
            u32 xb16 = f2bf(v);
            u32 other = (u32)__shfl_xor((int)xb16, 1, 64);
            if (nok && mr < 8 && !(lane & 1))
              st32sc((u32*)&xnxt[(size_t)(Bm0 + mr) * HLD + n], xb16 | (other << 16));
          }
        }
      }
    }
    if (t + 1 < NT) gridbar(p.bar, 2 * t + 2);
  }
}

// ---------------- prolog GEMM (QE, x0) ---------------------------------------
struct GemmZ {
  const u16* A; int lda;
  const u16* B; int ldb;
  int K;
  const float* bias;
  u16* C; int ldc;
  int mode;
};

__global__ __launch_bounds__(256, 2) void gemmP(GemmZ g)
{
  __shared__ u16 lA[2][128 * 32];
  __shared__ u16 lB[2][128 * 32];
  const int tid = threadIdx.x, lane = tid & 63, w = tid >> 6;
  const int wr = w >> 1, wc = w & 1;
  const size_t m0 = (size_t)blockIdx.y * 128;
  const int n0 = blockIdx.x * 128;
  const int r16 = lane & 15, k8g = lane >> 4;
  f32x4 acc[4][4] = {};

  const int S0 = tid, S1 = tid + 256;
  const int ar0 = S0 >> 2, ak0 = (((S0 & 3) - ((S0 >> 3) & 3)) & 3) * 8;
  const int ar1 = S1 >> 2, ak1 = (((S1 & 3) - ((S1 >> 3) & 3)) & 3) * 8;
  const int lo = w * 1024;
  const int niter = g.K / 32;

  auto stage = [&](int buf, int kc) {
    gll16(g.A + (m0 + ar0) * (size_t)g.lda + kc + ak0, (char*)lA[buf] + lo);
    gll16(g.A + (m0 + ar1) * (size_t)g.lda + kc + ak1, (char*)lA[buf] + 4096 + lo);
    gll16(g.B + (size_t)(n0 + ar0) * g.ldb + kc + ak0, (char*)lB[buf] + lo);
    gll16(g.B + (size_t)(n0 + ar1) * g.ldb + kc + ak1, (char*)lB[buf] + 4096 + lo);
  };
  auto compute = [&](int buf) {
    bf16x8 fa[4], fb[4];
#pragma unroll
    for (int i = 0; i < 4; i++) {
      int row = wr * 64 + i * 16 + r16;
      int S = row * 4 + ((k8g + (row >> 1)) & 3);
      fa[i] = *(const bf16x8*)((const char*)lA[buf] + S * 16);
    }
#pragma unroll
    for (int j = 0; j < 4; j++) {
      int row = wc * 64 + j * 16 + r16;
      int S = row * 4 + ((k8g + (row >> 1)) & 3);
      fb[j] = *(const bf16x8*)((const char*)lB[buf] + S * 16);
    }
#pragma unroll
    for (int i = 0; i < 4; i++)
#pragma unroll
      for (int j = 0; j < 4; j++)
        acc[i][j] = __builtin_amdgcn_mfma_f32_16x16x32_bf16(fa[i], fb[j], acc[i][j], 0, 0, 0);
  };

  stage(0, 0);
  __syncthreads();
  for (int it = 0; it < niter; ++it) {
    if (it + 1 < niter) stage((it + 1) & 1, (it + 1) * 32);
    compute(it & 1);
    __syncthreads();
  }

#pragma unroll
  for (int i = 0; i < 4; i++) {
    size_t mb = m0 + wr * 64 + i * 16 + k8g * 4;
#pragma unroll
    for (int j = 0; j < 4; j++) {
      int n = n0 + wc * 64 + j * 16 + r16;
      if (g.mode == 1) {
        if (n >= DP) continue;
        float b = (n < DET) ? g.bias[n] : 0.f;
#pragma unroll
        for (int r = 0; r < 4; r++)
          g.C[(mb + r) * (size_t)g.ldc + n] = f2bf(eluf(acc[i][j][r] + b));
      } else {
        if (n >= g.ldc) continue;
#pragma unroll
        for (int r = 0; r < 4; r++)
          g.C[(mb + r) * (size_t)g.ldc + n] = f2bf(acc[i][j][r]);
      }
    }
  }
}

// ---------------- small prolog kernels ---------------------------------------
__global__ void wconv_k(const float* src, int srows, int scols, int sstride,
                        u16* dst, int drows, int dstride, int c0, int cw)
{
  int idx = blockIdx.x * 256 + threadIdx.x;
  if (idx >= drows * cw) return;
  int r = idx / cw, c = idx - r * cw;
  float v = (r < srows && c < scols) ? src[(size_t)r * sstride + c] : 0.f;
  dst[(size_t)r * dstride + c0 + c] = f2bf(v);
}

__global__ void conv8_k(const float* src, u16* dst, int n8)
{
  int i = blockIdx.x * 256 + threadIdx.x;
  if (i >= n8) return;
  const float4* s = (const float4*)(src + (size_t)i * 8);
  float4 f0 = s[0], f1 = s[1];
  union { u16 h[8]; int4 v; } cv;
  cv.h[0] = f2bf(f0.x); cv.h[1] = f2bf(f0.y); cv.h[2] = f2bf(f0.z); cv.h[3] = f2bf(f0.w);
  cv.h[4] = f2bf(f1.x); cv.h[5] = f2bf(f1.y); cv.h[6] = f2bf(f1.z); cv.h[7] = f2bf(f1.w);
  *(int4*)(dst + (size_t)i * 8) = cv.v;
}

__global__ void xin0_k(const float* stoc0, const float* nt0, const float* act0, u16* xing)
{
  int i = blockIdx.x * 256 + threadIdx.x;
  if (i >= NB * 64) return;
  int m = i >> 6, c = i & 63;
  float v = 0.f;
  if (c < 32) v = stoc0[m * 32 + c] * nt0[m];
  else if (c < 38) v = act0[m * 6 + (c - 32)];
  xing[i] = f2bf(v);
}

// ---------------- host --------------------------------------------------------
extern "C" void kernel_launch(void* const* d_in, const int* in_sizes, int n_in,
                              void* d_out, int out_size, void* d_ws, size_t ws_size,
                              hipStream_t stream)
{
  const float* actions    = (const float*)d_in[0];
  const float* nonterm    = (const float*)d_in[1];
  const float* emb        = (const float*)d_in[2];
  const float* noise_p    = (const float*)d_in[3];
  const float* noise_q    = (const float*)d_in[4];
  const float* init_deter = (const float*)d_in[5];
  const float* init_stoc  = (const float*)d_in[6];
  const float* W_in = (const float*)d_in[7];
  const float* b_in = (const float*)d_in[8];
  const float* W_ih = (const float*)d_in[9];
  const float* b_ih = (const float*)d_in[10];
  const float* W_hh = (const float*)d_in[11];
  const float* b_hh = (const float*)d_in[12];
  const float* Wp1 = (const float*)d_in[13];
  const float* bp1 = (const float*)d_in[14];
  const float* Wp2 = (const float*)d_in[15];
  const float* bp2 = (const float*)d_in[16];
  const float* Wq1 = (const float*)d_in[17];
  const float* bq1 = (const float*)d_in[18];
  const float* Wq2 = (const float*)d_in[19];
  const float* bq2 = (const float*)d_in[20];
  float* out = (float*)d_out;

  char* wsp = (char*)d_ws;
  size_t o = 0;
  auto alloc = [&](size_t b) { char* pp = wsp + o; o = (o + b + 255) & ~(size_t)255; return pp; };
  u16* W6   = (u16*)alloc(6ull * NP * DP * 2);
  u16* Wp1p = (u16*)alloc((size_t)NP * DP * 2);
  u16* Wq1h = (u16*)alloc((size_t)NP * DP * 2);
  u16* Wq1e = (u16*)alloc((size_t)NP * EMB * 2);
  u16* Wp2p = (u16*)alloc(64ull * NP * 2);
  u16* Wq2p = (u16*)alloc(64ull * NP * 2);
  u16* Winp = (u16*)alloc((size_t)NP * 64 * 2);
  u16* xing = (u16*)alloc((size_t)NB * 64 * 2);
  u32* barp = (u32*)alloc(4096);
  u16* xbuf = (u16*)alloc(HXS2 * 2 * (NT + 1));
  u16* hbuf = (u16*)alloc(HXS2 * 2 * (NT + 1));
  u16* embb = (u16*)alloc((size_t)NT * NB * EMB * 2);
  u16* QE   = (u16*)alloc((size_t)NT * NB * NP * 2);
  if (o > ws_size) return;

  hipMemsetAsync(barp, 0, 4096, stream);

  auto wcl = [&](const float* src, int sr, int sc, int ss, u16* dst, int dr, int ds, int c0, int cw) {
    int n = dr * cw;
    wconv_k<<<(n + 255) / 256, 256, 0, stream>>>(src, sr, sc, ss, dst, dr, ds, c0, cw);
  };
  for (int s = 0; s < 3; s++) {
    wcl(W_ih + (size_t)s * 600 * 600, 600, 600, 600, W6 + (size_t)s * NP * DP, NP, DP, 0, DP);
    wcl(W_hh + (size_t)s * 600 * 600, 600, 600, 600, W6 + (size_t)(3 + s) * NP * DP, NP, DP, 0, DP);
  }
  wcl(Wp1, 600, 600, 600, Wp1p, NP, DP, 0, DP);
  wcl(Wq1, 600, 600, 1624, Wq1h, NP, DP, 0, DP);
  wcl(Wq1 + 600, 600, 1024, 1624, Wq1e, NP, EMB, 0, EMB);
  wcl(Wp2, 64, 600, 600, Wp2p, 64, NP, 0, NP);
  wcl(Wq2, 64, 600, 600, Wq2p, 64, NP, 0, NP);
  wcl(W_in, 600, 38, 38, Winp, NP, 64, 0, 64);
  wcl(init_deter, 1024, 600, 600, hbuf, 1024, HLD, 0, DP);

  {
    int n8 = NT * NB * EMB / 8;
    conv8_k<<<(n8 + 255) / 256, 256, 0, stream>>>(emb, embb, n8);
    GemmZ gq = { embb, EMB, Wq1e, EMB, EMB, nullptr, QE, NP, 2 };
    gemmP<<<dim3(5, 400, 1), 256, 0, stream>>>(gq);
  }
  xin0_k<<<NB * 64 / 256, 256, 0, stream>>>(init_stoc, nonterm, actions, xing);
  {
    GemmZ gx = { xing, 64, Winp, 64, 64, b_in, xbuf, HLD, 1 };
    gemmP<<<dim3(5, 8, 1), 256, 0, stream>>>(gx);
  }

  PK pk = { W6, Wp1p, Wq1h, Wp2p, Wq2p, Winp, QE,
            b_ih, b_hh, bp1, bq1, bp2, bq2, b_in,
            init_deter, actions, nonterm, noise_p, noise_q,
            xbuf, hbuf, out, barp };
  rssm_persist<<<GBLK, 256, 0, stream>>>(pk);
}

// Round 11
// 5970.585 us; speedup vs baseline: 1.1980x; 1.1980x over previous
//
#include <hip/hip_runtime.h>

typedef __bf16 bf16x8 __attribute__((ext_vector_type(8)));
typedef float f32x4 __attribute__((ext_vector_type(4)));
typedef unsigned short u16;
typedef unsigned int u32;
typedef unsigned long long u64;

#define NT 50
#define NB 1024
#define DET 600
#define DP 608        // padded K dim 600 -> 19*32
#define NP 640        // padded N dim (weight rows)
#define EMB 1024
#define OUTW 792

__device__ __forceinline__ u16 f2bf(float f) {
  unsigned u = __float_as_uint(f);
  u += 0x7FFFu + ((u >> 16) & 1u);
  return (u16)(u >> 16);
}
__device__ __forceinline__ float bf2f(u16 h) { return __uint_as_float(((unsigned)h) << 16); }
__device__ __forceinline__ float eluf(float x) { return x > 0.f ? x : expm1f(x); }
__device__ __forceinline__ float sigm(float x) { return 1.f / (1.f + expf(-x)); }
__device__ __forceinline__ float softplusf(float x) {
  return fmaxf(x, 0.f) + log1pf(expf(-fabsf(x)));
}

__device__ __forceinline__ void gll16(const void* g, void* l) {
  __builtin_amdgcn_global_load_lds(
      (const __attribute__((address_space(1))) u32*)g,
      (__attribute__((address_space(3))) u32*)l, 16, 0, 0);
}

// Swizzled chunk layout for [rows][32] bf16 tiles staged as 16B chunks:
// chunk S holds (row = S>>2, k8 = ((S&3) - ((S>>3)&3)) & 3).
// reader for (row,k8): S = row*4 + ((k8 + (row>>1)) & 3)  -> 2-way banks (free).

// =================== kernel A: GRU (160 blocks, 64KB LDS) ===================
struct GruP {
  const u16 *xb, *hb, *W6;
  const float *b_ih, *b_hh;
  const float *dprev; int dstride;
  float *out_t; u16 *hbn;
};

__global__ __launch_bounds__(256, 1) void gru_k(GruP p)
{
  __shared__ char smem[65536] __attribute__((aligned(16)));
  const int bid = blockIdx.x, tid = threadIdx.x;
  const int lane = tid & 63, w = tid >> 6;
  const int r16 = lane & 15, k8g = lane >> 4;

  // 2-D XCD-affine mapping (R8-verified): XCD = bid%8 = (my%4)*2 + (nx%2)
  const int xg = bid & 7, gg = bid >> 3;
  const int my = (gg & 3) * 4 + (xg >> 1);   // 0..15
  const int nx = (gg >> 2) * 2 + (xg & 1);   // 0..9
  const int Am0 = my * 64, An0 = nx * 64;
  const int wr = w >> 1, wc = w & 1;
  const int srow = tid >> 2;
  const int sk8 = ((tid & 3) - ((tid >> 3) & 3)) & 3;
  const int lo = w * 1024;
  const u16* bw[6];
#pragma unroll
  for (int s = 0; s < 6; s++)
    bw[s] = p.W6 + (size_t)s * NP * DP + (size_t)(An0 + srow) * DP + sk8 * 8;
  const u16* axp = p.xb + (size_t)(Am0 + srow) * DP + sk8 * 8;
  const u16* ahp = p.hb + (size_t)(Am0 + srow) * DP + sk8 * 8;

  auto ldsT = [&](int buf, int tile) -> char* { return smem + buf * 32768 + tile * 4096; };
  f32x4 acc[6][2][2] = {};
  auto stage = [&](int buf, int kc) {
    gll16(axp + kc, ldsT(buf, 0) + lo);
    gll16(ahp + kc, ldsT(buf, 1) + lo);
#pragma unroll
    for (int s = 0; s < 6; s++) gll16(bw[s] + kc, ldsT(buf, 2 + s) + lo);
  };
  auto compute = [&](int buf) {
    bf16x8 ax_[2], ah_[2];
#pragma unroll
    for (int i = 0; i < 2; i++) {
      int row = wr * 32 + i * 16 + r16;
      int S = row * 4 + ((k8g + (row >> 1)) & 3);
      ax_[i] = *(const bf16x8*)(ldsT(buf, 0) + S * 16);
      ah_[i] = *(const bf16x8*)(ldsT(buf, 1) + S * 16);
    }
#pragma unroll
    for (int s = 0; s < 6; s++) {
#pragma unroll
      for (int j = 0; j < 2; j++) {
        int row = wc * 32 + j * 16 + r16;
        int S = row * 4 + ((k8g + (row >> 1)) & 3);
        bf16x8 b = *(const bf16x8*)(ldsT(buf, 2 + s) + S * 16);
#pragma unroll
        for (int i = 0; i < 2; i++)
          acc[s][i][j] = __builtin_amdgcn_mfma_f32_16x16x32_bf16(
              (s < 3) ? ax_[i] : ah_[i], b, acc[s][i][j], 0, 0, 0);
      }
    }
  };
  // counted-vmcnt software pipeline: next-tile loads stay in flight (T4)
  stage(0, 0);
  for (int it = 0; it < 19; ++it) {
    if (it + 1 < 19) {
      stage((it + 1) & 1, (it + 1) * 32);
      asm volatile("s_waitcnt vmcnt(8)" ::: "memory");
    } else {
      asm volatile("s_waitcnt vmcnt(0)" ::: "memory");
    }
    __builtin_amdgcn_s_barrier();
    __builtin_amdgcn_sched_barrier(0);
    compute(it & 1);
    __builtin_amdgcn_s_barrier();
  }

#pragma unroll
  for (int j = 0; j < 2; j++) {
    int n = An0 + wc * 32 + j * 16 + r16;
    bool nok = (n < DET);
    float bihr = nok ? p.b_ih[n] : 0.f, bhhr = nok ? p.b_hh[n] : 0.f;
    float bihz = nok ? p.b_ih[600 + n] : 0.f, bhhz = nok ? p.b_hh[600 + n] : 0.f;
    float bihn = nok ? p.b_ih[1200 + n] : 0.f, bhhn = nok ? p.b_hh[1200 + n] : 0.f;
#pragma unroll
    for (int i = 0; i < 2; i++) {
      int mb = Am0 + wr * 32 + i * 16 + k8g * 4;
#pragma unroll
      for (int r = 0; r < 4; r++) {
        int m = mb + r;
        float dp = nok ? p.dprev[(size_t)m * p.dstride + n] : 0.f;
        float rg = sigm(acc[0][i][j][r] + bihr + acc[3][i][j][r] + bhhr);
        float zg = sigm(acc[1][i][j][r] + bihz + acc[4][i][j][r] + bhhz);
        float ng = tanhf(acc[2][i][j][r] + bihn + rg * (acc[5][i][j][r] + bhhn));
        float h = (1.f - zg) * ng + zg * dp;
        if (nok) {
          p.out_t[(size_t)m * OUTW + n] = h;
          p.hbn[(size_t)m * DP + n] = f2bf(h);   // pads never written (mul by 0 W-cols)
        }
      }
    }
  }
}

// ========= kernel B: heads1+heads2+sampling+xnext (256 blocks, 32KB) =========
struct HdP {
  const u16 *hb, *Wp1, *Wq1h, *Wp2, *Wq2, *Winp, *QEt;
  const float *bp1, *bq1, *bp2, *bq2, *b_in;
  const float *np_t, *nq_t;
  const float *ntn, *an;     // nonterm/actions for t+1; null at t=NT-1
  float *out_t; u16 *xb;
};

__global__ __launch_bounds__(256, 2) void headsx_k(HdP p)
{
  __shared__ char smem[32768] __attribute__((aligned(16)));
  const int bid = blockIdx.x, tid = threadIdx.x;
  const int lane = tid & 63, w = tid >> 6;
  const int r16 = lane & 15, k8g = lane >> 4;

  // XCD<->head affinity: xcd = bid%8; head = xcd>>2; slice = (bid>>3)*4 + (xcd&3)
  const int xcd = bid & 7;
  const int head = xcd >> 2;
  const int slice = (bid >> 3) * 4 + (xcd & 3);   // 0..127
  const int Bm0 = slice * 8;
  const u16* W1 = head ? p.Wq1h : p.Wp1;
  const float* b1 = head ? p.bq1 : p.bp1;
  const u16* W2 = head ? p.Wq2 : p.Wp2;
  const float* b2 = head ? p.bq2 : p.bp2;
  const float* noise = head ? p.nq_t : p.np_t;
  const bool donext = p.ntn != nullptr;

  u16* hslph = (u16*)smem;                 // hsl [8][616] then ph [16][648] (aliased)
  float* red = (float*)(smem + 20736);     // [3][64][8] f32
  u16* xin = (u16*)(smem + 26880);         // [16][72] bf16

  // stage h slice [8][608] -> hsl [8][616] (616 chunks; 77th per row duplicates)
  {
    const u16* hrow = p.hb + (size_t)Bm0 * DP;
#pragma unroll
    for (int c = 0; c < 3; ++c) {
      int chunk = c * 256 + tid;
      int ch2 = chunk < 616 ? chunk : 615;
      int row = ch2 / 77, cc = ch2 - row * 77;
      int scc = cc < 76 ? cc : 75;
      gll16(hrow + (size_t)row * DP + scc * 8, smem + (c * 256 + w * 64) * 16);
    }
  }
  // QE prefetch (rows mr<8)
  float qe[10][4] = {};
  if (head) {
#pragma unroll
    for (int i = 0; i < 10; i++) {
      int j = w + i * 4;
      if (j < 38) {
        int n = j * 16 + r16;
#pragma unroll
        for (int r = 0; r < 4; r++) {
          int mr = k8g * 4 + r;
          if (mr < 8) qe[i][r] = bf2f(p.QEt[((size_t)(Bm0 + mr)) * NP + n]);
        }
      }
    }
  }
  if (donext)
    for (int i = tid; i < 576; i += 256) ((u32*)xin)[i] = 0;
  __syncthreads();

  // heads1: [8(pad16) rows] x [608 cols], K=608; A from LDS, W1 direct (L2)
  f32x4 a1[10] = {};
  for (int kc = 0; kc < DP; kc += 32) {
    bf16x8 fa = *(const bf16x8*)&hslph[r16 * 616 + kc + k8g * 8];
#pragma unroll
    for (int i = 0; i < 10; i++) {
      int j = w + i * 4;
      if (j < 38) {
        bf16x8 fb = *(const bf16x8*)&W1[(size_t)(j * 16 + r16) * DP + kc + k8g * 8];
        a1[i] = __builtin_amdgcn_mfma_f32_16x16x32_bf16(fa, fb, a1[i], 0, 0, 0);
      }
    }
  }
  __syncthreads();   // hsl reads done before ph (aliased) writes
  // zero ph cols 600..647 (all 16 rows) -- NaN hygiene for heads2 K-pad
  for (int i = tid; i < 384; i += 256) {
    int r = i / 24, c = i - r * 24;
    *(u32*)&hslph[r * 648 + 600 + 2 * c] = 0;
  }
  // ph epilogue: elu(+bias +QE) -> LDS bf16 [16][648] (rows>=8 garbage, confined)
#pragma unroll
  for (int i = 0; i < 10; i++) {
    int j = w + i * 4;
    if (j >= 38) break;
    int n = j * 16 + r16;
    if (n >= DET) continue;
#pragma unroll
    for (int r = 0; r < 4; r++) {
      int mrow = k8g * 4 + r;
      float v = a1[i][r] + b1[n] + qe[i][r];
      hslph[mrow * 648 + n] = f2bf(eluf(v));
    }
  }
  __syncthreads();
  // heads2: K=640 split over 4 waves (W2 k>=600 zero-padded)
  f32x4 a2[4] = {};
  {
    int kc0 = w * 160;
#pragma unroll
    for (int ks = 0; ks < 5; ks++) {
      int kc = kc0 + ks * 32;
      bf16x8 fa = *(const bf16x8*)&hslph[r16 * 648 + kc + k8g * 8];
#pragma unroll
      for (int j = 0; j < 4; j++) {
        bf16x8 fb = *(const bf16x8*)&W2[(size_t)(j * 16 + r16) * NP + kc + k8g * 8];
        a2[j] = __builtin_amdgcn_mfma_f32_16x16x32_bf16(fa, fb, a2[j], 0, 0, 0);
      }
    }
  }
  if (w) {
#pragma unroll
    for (int j = 0; j < 4; j++)
#pragma unroll
      for (int r = 0; r < 4; r++) {
        int mr = k8g * 4 + r;
        if (mr < 8) red[(w - 1) * 512 + (j * 16 + r16) * 8 + mr] = a2[j][r];
      }
  }
  __syncthreads();
  if (w == 0) {
    const int ob = head ? 696 : 600;
#pragma unroll
    for (int j = 0; j < 2; j++) {
      int c = j * 16 + r16;
      float bmu = b2[c], bsd = b2[32 + c];
#pragma unroll
      for (int r = 0; r < 4; r++) {
        int mr = k8g * 4 + r;
        if (mr >= 8) continue;
        int m = Bm0 + mr;
        float mu = a2[j][r] + red[c * 8 + mr] + red[512 + c * 8 + mr]
                 + red[1024 + c * 8 + mr] + bmu;
        float s2 = a2[j + 2][r] + red[(32 + c) * 8 + mr]
                 + red[512 + (32 + c) * 8 + mr] + red[1024 + (32 + c) * 8 + mr] + bsd;
        float sd = softplusf(s2) + 0.1f;
        float st = mu + sd * noise[(size_t)m * 32 + c];
        float* op = p.out_t + (size_t)m * OUTW + ob;
        op[c] = mu; op[32 + c] = sd; op[64 + c] = st;
        if (head && donext) xin[mr * 72 + c] = f2bf(st * p.ntn[m]);
      }
    }
  } else if (w == 1 && head && donext) {
    if (lane < 48) {
      int rr = lane / 6, cc = lane - rr * 6;
      xin[rr * 72 + 32 + cc] = f2bf(p.an[(size_t)(Bm0 + rr) * 6 + cc]);
    }
  }
  if (head && donext) {
    __syncthreads();
    // xnext: elu(xin[8(pad16)][64] @ Winp^T + b_in) -> xb rows Bm0..Bm0+7
    f32x4 xc[10] = {};
    const int nb = w * 160;
#pragma unroll
    for (int kc = 0; kc < 64; kc += 32) {
      bf16x8 fa = *(const bf16x8*)&xin[r16 * 72 + kc + k8g * 8];
#pragma unroll
      for (int j = 0; j < 10; j++) {
        bf16x8 fb = *(const bf16x8*)&p.Winp[(size_t)(nb + j * 16 + r16) * 64 + kc + k8g * 8];
        xc[j] = __builtin_amdgcn_mfma_f32_16x16x32_bf16(fa, fb, xc[j], 0, 0, 0);
      }
    }
#pragma unroll
    for (int j = 0; j < 10; j++) {
      int n = nb + j * 16 + r16;
      if (n >= DET) continue;
      float bi = p.b_in[n];
#pragma unroll
      for (int r = 0; r < 4; r++) {
        int mr = k8g * 4 + r;
        if (mr < 8)
          p.xb[(size_t)(Bm0 + mr) * DP + n] = f2bf(eluf(xc[j][r] + bi));
      }
    }
  }
}

// ---------------- prolog GEMM (QE, x0) ---------------------------------------
struct GemmZ {
  const u16* A; int lda;
  const u16* B; int ldb;
  int K;
  const float* bias;
  u16* C; int ldc;
  int mode;   // 1: elu(x+bias[n<DET]) -> bf16, store n<DP ; 2: raw bf16, store n<ldc
};

__global__ __launch_bounds__(256, 2) void gemmP(GemmZ g)
{
  __shared__ u16 lA[2][128 * 32];
  __shared__ u16 lB[2][128 * 32];
  const int tid = threadIdx.x, lane = tid & 63, w = tid >> 6;
  const int wr = w >> 1, wc = w & 1;
  const size_t m0 = (size_t)blockIdx.y * 128;
  const int n0 = blockIdx.x * 128;
  const int r16 = lane & 15, k8g = lane >> 4;
  f32x4 acc[4][4] = {};

  const int S0 = tid, S1 = tid + 256;
  const int ar0 = S0 >> 2, ak0 = (((S0 & 3) - ((S0 >> 3) & 3)) & 3) * 8;
  const int ar1 = S1 >> 2, ak1 = (((S1 & 3) - ((S1 >> 3) & 3)) & 3) * 8;
  const int lo = w * 1024;
  const int niter = g.K / 32;

  auto stage = [&](int buf, int kc) {
    gll16(g.A + (m0 + ar0) * (size_t)g.lda + kc + ak0, (char*)lA[buf] + lo);
    gll16(g.A + (m0 + ar1) * (size_t)g.lda + kc + ak1, (char*)lA[buf] + 4096 + lo);
    gll16(g.B + (size_t)(n0 + ar0) * g.ldb + kc + ak0, (char*)lB[buf] + lo);
    gll16(g.B + (size_t)(n0 + ar1) * g.ldb + kc + ak1, (char*)lB[buf] + 4096 + lo);
  };
  auto compute = [&](int buf) {
    bf16x8 fa[4], fb[4];
#pragma unroll
    for (int i = 0; i < 4; i++) {
      int row = wr * 64 + i * 16 + r16;
      int S = row * 4 + ((k8g + (row >> 1)) & 3);
      fa[i] = *(const bf16x8*)((const char*)lA[buf] + S * 16);
    }
#pragma unroll
    for (int j = 0; j < 4; j++) {
      int row = wc * 64 + j * 16 + r16;
      int S = row * 4 + ((k8g + (row >> 1)) & 3);
      fb[j] = *(const bf16x8*)((const char*)lB[buf] + S * 16);
    }
#pragma unroll
    for (int i = 0; i < 4; i++)
#pragma unroll
      for (int j = 0; j < 4; j++)
        acc[i][j] = __builtin_amdgcn_mfma_f32_16x16x32_bf16(fa[i], fb[j], acc[i][j], 0, 0, 0);
  };

  stage(0, 0);
  __syncthreads();
  for (int it = 0; it < niter; ++it) {
    if (it + 1 < niter) stage((it + 1) & 1, (it + 1) * 32);
    compute(it & 1);
    __syncthreads();
  }

#pragma unroll
  for (int i = 0; i < 4; i++) {
    size_t mb = m0 + wr * 64 + i * 16 + k8g * 4;
#pragma unroll
    for (int j = 0; j < 4; j++) {
      int n = n0 + wc * 64 + j * 16 + r16;
      if (g.mode == 1) {
        if (n >= DP) continue;
        float b = (n < DET) ? g.bias[n] : 0.f;
#pragma unroll
        for (int r = 0; r < 4; r++)
          g.C[(mb + r) * (size_t)g.ldc + n] = f2bf(eluf(acc[i][j][r] + b));
      } else {
        if (n >= g.ldc) continue;
#pragma unroll
        for (int r = 0; r < 4; r++)
          g.C[(mb + r) * (size_t)g.ldc + n] = f2bf(acc[i][j][r]);
      }
    }
  }
}

// ---------------- small prolog kernels ---------------------------------------
__global__ void wconv_k(const float* src, int srows, int scols, int sstride,
                        u16* dst, int drows, int dstride, int c0, int cw)
{
  int idx = blockIdx.x * 256 + threadIdx.x;
  if (idx >= drows * cw) return;
  int r = idx / cw, c = idx - r * cw;
  float v = (r < srows && c < scols) ? src[(size_t)r * sstride + c] : 0.f;
  dst[(size_t)r * dstride + c0 + c] = f2bf(v);
}

__global__ void conv8_k(const float* src, u16* dst, int n8)
{
  int i = blockIdx.x * 256 + threadIdx.x;
  if (i >= n8) return;
  const float4* s = (const float4*)(src + (size_t)i * 8);
  float4 f0 = s[0], f1 = s[1];
  union { u16 h[8]; int4 v; } cv;
  cv.h[0] = f2bf(f0.x); cv.h[1] = f2bf(f0.y); cv.h[2] = f2bf(f0.z); cv.h[3] = f2bf(f0.w);
  cv.h[4] = f2bf(f1.x); cv.h[5] = f2bf(f1.y); cv.h[6] = f2bf(f1.z); cv.h[7] = f2bf(f1.w);
  *(int4*)(dst + (size_t)i * 8) = cv.v;
}

__global__ void xin0_k(const float* stoc0, const float* nt0, const float* act0, u16* xing)
{
  int i = blockIdx.x * 256 + threadIdx.x;
  if (i >= NB * 64) return;
  int m = i >> 6, c = i & 63;
  float v = 0.f;
  if (c < 32) v = stoc0[m * 32 + c] * nt0[m];
  else if (c < 38) v = act0[m * 6 + (c - 32)];
  xing[i] = f2bf(v);
}

// ---------------- host --------------------------------------------------------
extern "C" void kernel_launch(void* const* d_in, const int* in_sizes, int n_in,
                              void* d_out, int out_size, void* d_ws, size_t ws_size,
                              hipStream_t stream)
{
  const float* actions    = (const float*)d_in[0];
  const float* nonterm    = (const float*)d_in[1];
  const float* emb        = (const float*)d_in[2];
  const float* noise_p    = (const float*)d_in[3];
  const float* noise_q    = (const float*)d_in[4];
  const float* init_deter = (const float*)d_in[5];
  const float* init_stoc  = (const float*)d_in[6];
  const float* W_in = (const float*)d_in[7];
  const float* b_in = (const float*)d_in[8];
  const float* W_ih = (const float*)d_in[9];
  const float* b_ih = (const float*)d_in[10];
  const float* W_hh = (const float*)d_in[11];
  const float* b_hh = (const float*)d_in[12];
  const float* Wp1 = (const float*)d_in[13];
  const float* bp1 = (const float*)d_in[14];
  const float* Wp2 = (const float*)d_in[15];
  const float* bp2 = (const float*)d_in[16];
  const float* Wq1 = (const float*)d_in[17];
  const float* bq1 = (const float*)d_in[18];
  const float* Wq2 = (const float*)d_in[19];
  const float* bq2 = (const float*)d_in[20];
  float* out = (float*)d_out;

  char* wsp = (char*)d_ws;
  size_t o = 0;
  auto alloc = [&](size_t b) { char* pp = wsp + o; o = (o + b + 255) & ~(size_t)255; return pp; };
  u16* W6   = (u16*)alloc(6ull * NP * DP * 2);
  u16* Wp1p = (u16*)alloc((size_t)NP * DP * 2);
  u16* Wq1h = (u16*)alloc((size_t)NP * DP * 2);
  u16* Wq1e = (u16*)alloc((size_t)NP * EMB * 2);
  u16* Wp2p = (u16*)alloc(64ull * NP * 2);
  u16* Wq2p = (u16*)alloc(64ull * NP * 2);
  u16* Winp = (u16*)alloc((size_t)NP * 64 * 2);
  u16* xing = (u16*)alloc((size_t)NB * 64 * 2);
  u16* xb   = (u16*)alloc((size_t)NB * DP * 2);
  u16* hb0  = (u16*)alloc((size_t)NB * DP * 2);
  u16* hb1  = (u16*)alloc((size_t)NB * DP * 2);
  u16* embb = (u16*)alloc((size_t)NT * NB * EMB * 2);
  u16* QE   = (u16*)alloc((size_t)NT * NB * NP * 2);
  if (o > ws_size) return;

  auto wcl = [&](const float* src, int sr, int sc, int ss, u16* dst, int dr, int ds, int c0, int cw) {
    int n = dr * cw;
    wconv_k<<<(n + 255) / 256, 256, 0, stream>>>(src, sr, sc, ss, dst, dr, ds, c0, cw);
  };
  for (int s = 0; s < 3; s++) {
    wcl(W_ih + (size_t)s * 600 * 600, 600, 600, 600, W6 + (size_t)s * NP * DP, NP, DP, 0, DP);
    wcl(W_hh + (size_t)s * 600 * 600, 600, 600, 600, W6 + (size_t)(3 + s) * NP * DP, NP, DP, 0, DP);
  }
  wcl(Wp1, 600, 600, 600, Wp1p, NP, DP, 0, DP);
  wcl(Wq1, 600, 600, 1624, Wq1h, NP, DP, 0, DP);
  wcl(Wq1 + 600, 600, 1024, 1624, Wq1e, NP, EMB, 0, EMB);
  wcl(Wp2, 64, 600, 600, Wp2p, 64, NP, 0, NP);
  wcl(Wq2, 64, 600, 600, Wq2p, 64, NP, 0, NP);
  wcl(W_in, 600, 38, 38, Winp, NP, 64, 0, 64);
  wcl(init_deter, 1024, 600, 600, hb0, 1024, DP, 0, DP);

  // QE = emb @ Wq1e^T for all T (off critical path)
  {
    int n8 = NT * NB * EMB / 8;
    conv8_k<<<(n8 + 255) / 256, 256, 0, stream>>>(emb, embb, n8);
    GemmZ gq = { embb, EMB, Wq1e, EMB, EMB, nullptr, QE, NP, 2 };
    gemmP<<<dim3(5, 400, 1), 256, 0, stream>>>(gq);
  }
  // x_0 -> xb
  xin0_k<<<NB * 64 / 256, 256, 0, stream>>>(init_stoc, nonterm, actions, xing);
  {
    GemmZ gx = { xing, 64, Winp, 64, 64, b_in, xb, DP, 1 };
    gemmP<<<dim3(5, 8, 1), 256, 0, stream>>>(gx);
  }

  for (int t = 0; t < NT; t++) {
    float* out_t = out + (size_t)t * NB * OUTW;
    u16* hcur = (t & 1) ? hb1 : hb0;
    u16* hnxt = (t & 1) ? hb0 : hb1;
    const float* dprev = (t == 0) ? init_deter : out + (size_t)(t - 1) * NB * OUTW;
    int dstr = (t == 0) ? DET : OUTW;

    GruP gp = { xb, hcur, W6, b_ih, b_hh, dprev, dstr, out_t, hnxt };
    gru_k<<<160, 256, 0, stream>>>(gp);

    HdP hp = { hnxt, Wp1p, Wq1h, Wp2p, Wq2p, Winp, QE + (size_t)t * NB * NP,
               bp1, bq1, bp2, bq2, b_in,
               noise_p + (size_t)t * NB * 32, noise_q + (size_t)t * NB * 32,
               (t + 1 < NT) ? nonterm + (size_t)(t + 1) * NB : nullptr,
               (t + 1 < NT) ? actions + (size_t)(t + 1) * NB * 6 : nullptr,
               out_t, xb };
    headsx_k<<<256, 256, 0, stream>>>(hp);
  }
}